// Round 4
// baseline (156.112 us; speedup 1.0000x reference)
//
#include <hip/hip_runtime.h>
#include <cstdint>
#include <cstddef>

#define S_CELLS 4096   // 64*64
#define NB      8
#define NPTS    8192
#define E       128
#define MAXP    20
#define NHEADS  8
#define NPT_ROWS 65536
#define NGR_ROWS 32768

// ws layout (bytes):
#define WS_COUNTS 0          // int[32768]        (131072)
#define WS_SLOTS  131072     // int[32768*20]     (2621440)
#define WS_WT1    2752512    // bf16 144x136      (40960 w/ pad)
#define WS_WT2    2793472    // bf16 128x136      (34816)
#define WS_SC     2828288    // float[98304*8]    (3145728)

typedef __attribute__((ext_vector_type(8))) short bf16x8;
typedef __attribute__((ext_vector_type(4))) float f32x4;

__device__ __forceinline__ unsigned short f2bf_bits(float f) {   // RNE (cold paths)
    unsigned u = __float_as_uint(f);
    unsigned rounded = u + 0x7FFFu + ((u >> 16) & 1u);
    return (unsigned short)(rounded >> 16);
}
__device__ __forceinline__ unsigned short f2bf_rta(float f) {    // round-ties-away (hot)
    return (unsigned short)((__float_as_uint(f) + 0x8000u) >> 16);
}
__device__ __forceinline__ unsigned pack_bf2(float a, float b) { // [b|a] packed bf16 (RTA)
    unsigned ua = __float_as_uint(a) + 0x8000u;
    unsigned ub = __float_as_uint(b) + 0x8000u;
    return (ua >> 16) | (ub & 0xFFFF0000u);
}

// ---------------------------------------------------------------------------
// Kernel 1 (9 blocks x 256): zero counts (striped) +
//   block 0    : q = latent@Wq; A[i][h]=(Wk[i,h*16:+16].q_h)/4 -> WT1 rows
//                128..135; zero rows 136..143
//   blocks 1..4: Wv -> WT1 rows 0..127 (bf16, transposed [n][k], stride 136)
//   blocks 5..8: Wo -> WT2 (same layout)
// ---------------------------------------------------------------------------
__global__ void __launch_bounds__(256)
k_prep(const float* __restrict__ latent,
       const float* __restrict__ Wq,
       const float* __restrict__ Wk,
       const float* __restrict__ Wv,
       const float* __restrict__ Wo,
       int* __restrict__ counts,
       unsigned short* __restrict__ WT1,
       unsigned short* __restrict__ WT2) {
    const int t   = threadIdx.x;
    const int blk = blockIdx.x;

    {   // zero counts: 8192 int4s across 9*256 threads
        int4* c4 = (int4*)counts;
        for (int idx = blk * 256 + t; idx < 8192; idx += 9 * 256)
            c4[idx] = int4{0, 0, 0, 0};
    }

    if (blk == 0) {
        __shared__ float lat[E];
        __shared__ float qv[E];
        const int j = t & 127;
        if (t < E) lat[t] = latent[t];
        __syncthreads();
        float acc = 0.0f;                    // both halves compute identical q[j]
        for (int k2 = 0; k2 < E; ++k2) acc += lat[k2] * Wq[k2 * E + j];
        qv[j] = acc;
        __syncthreads();
        const int hb = (t >> 7) * 4;
        for (int h = hb; h < hb + 4; ++h) {
            float a = 0.0f;
            #pragma unroll
            for (int d = 0; d < 16; ++d) a += Wk[j * E + h * 16 + d] * qv[h * 16 + d];
            WT1[(size_t)(128 + h) * 136 + j] = f2bf_bits(a * 0.25f);
        }
        for (int idx = t; idx < 8 * 136; idx += 256) {   // zero rows 136..143
            int rr = idx / 136, cc = idx - rr * 136;
            WT1[(size_t)(136 + rr) * 136 + cc] = 0;
        }
        return;
    }

    // weight conversion: transpose via LDS, coalesced in and out
    const float* W = (blk < 5) ? Wv : Wo;
    unsigned short* WT = (blk < 5) ? WT1 : WT2;
    const int n0 = ((blk - 1) & 3) * 32;
    __shared__ float lbuf[128][33];
    #pragma unroll
    for (int it = 0; it < 16; ++it) {
        int k  = (t >> 5) + it * 8;
        int nl = t & 31;
        lbuf[k][nl] = W[(size_t)k * E + n0 + nl];
    }
    __syncthreads();
    for (int idx = t; idx < 32 * 136; idx += 256) {
        int nl = idx / 136, k = idx - nl * 136;
        float v = (k < 128) ? lbuf[k][nl] : 0.0f;
        WT[(size_t)(n0 + nl) * 136 + k] = f2bf_bits(v);
    }
}

// ---------------------------------------------------------------------------
// Kernel 2 (1024 blocks x 256): SLIM (no V materialization).
//   blocks 0..767  : SC = X @ A only (A = WT1 rows 128..143 staged, 4.4 KB).
//                    8 MFMAs/wave (was 72). Swapped operands -> lane owns
//                    row rb=..+cn, head-cols q*4+r -> one f32x4 store (q<2).
//   blocks 768..1023: per-point binning + x_grid passthrough copy.
// The big V GEMM is deleted: attention commutes with the Wv projection
// (out_h = (sum_t w_th z_t) @ Wv_h), handled in k_attn_proj.
// ---------------------------------------------------------------------------
__device__ __forceinline__ bf16x8 load_afrag_f32(const float* __restrict__ X,
                                                 int row, int kq, int q) {
    const float4* xr = (const float4*)(X + (size_t)row * E);
    float4 lo = xr[kq * 8 + q * 2];
    float4 hi = xr[kq * 8 + q * 2 + 1];
    unsigned u[4];
    u[0] = pack_bf2(lo.x, lo.y);
    u[1] = pack_bf2(lo.z, lo.w);
    u[2] = pack_bf2(hi.x, hi.y);
    u[3] = pack_bf2(hi.z, hi.w);
    union { unsigned u4[4]; bf16x8 v; } cv;
    cv.u4[0] = u[0]; cv.u4[1] = u[1]; cv.u4[2] = u[2]; cv.u4[3] = u[3];
    return cv.v;
}

__global__ void __launch_bounds__(256)
k_main(const float* __restrict__ x,
       const float* __restrict__ x_grid,
       const float* __restrict__ Xz,
       const float* __restrict__ Xg,
       const unsigned short* __restrict__ WT1g,
       int* __restrict__ counts,
       int* __restrict__ slots,
       float* __restrict__ SC,
       float* __restrict__ out_xgrid) {
    __shared__ __align__(16) unsigned short sA[16 * 136];   // 4352 B

    const int t = threadIdx.x;

    if (blockIdx.x >= 768) {                 // ---- binning + x_grid copy
        int i = (blockIdx.x - 768) * 256 + t;   // 0..65535
        out_xgrid[i] = x_grid[i];
        int b = i >> 13;
        float x0 = x[(size_t)i * 2 + 0];
        float x1 = x[(size_t)i * 2 + 1];
        int i0 = (int)rintf(x0 * 63.0f);     // RNE matches jnp.round
        int i1 = (int)rintf(x1 * 63.0f);
        i0 = min(max(i0, 0), 63);
        i1 = min(max(i1, 0), 63);
        int cell = b * S_CELLS + i0 * 64 + i1;
        int slot = atomicAdd(&counts[cell], 1);
        if (slot < MAXP) slots[(size_t)cell * MAXP + slot] = i & (NPTS - 1);
        return;
    }

    {   // stage A image: WT1 rows 128..143 (16x136 bf16 = 272 float4)
        const float4* src = (const float4*)(WT1g + 128 * 136);
        float4* dst = (float4*)sA;
        if (t < 272) dst[t] = src[t];
    }
    __syncthreads();

    const int lane = t & 63;
    const int wv   = t >> 6;
    const int cn   = lane & 15;
    const int q    = lane >> 4;

    const int grow0 = blockIdx.x * 128;
    const float* Xsrc;
    int srow;
    if (blockIdx.x < 512) { Xsrc = Xz; srow = grow0; }
    else                  { Xsrc = Xg; srow = grow0 - NPT_ROWS; }

    f32x4 acc[2];
    acc[0] = f32x4{0.0f, 0.0f, 0.0f, 0.0f};
    acc[1] = f32x4{0.0f, 0.0f, 0.0f, 0.0f};

    #pragma unroll
    for (int kq = 0; kq < 4; ++kq) {
        const bf16x8 b = *(const bf16x8*)&sA[cn * 136 + kq * 32 + q * 8];
        #pragma unroll
        for (int mt = 0; mt < 2; ++mt) {
            bf16x8 a = load_afrag_f32(Xsrc, srow + wv * 32 + mt * 16 + cn, kq, q);
            acc[mt] = __builtin_amdgcn_mfma_f32_16x16x32_bf16(b, a, acc[mt], 0, 0, 0);
        }
    }

    // swapped-D: lane owns row rb, head-cols q*4+{0..3}; cols 8..15 hit the
    // zero rows of A (WT1 rows 136..143) -> only q<2 stores.
    #pragma unroll
    for (int mt = 0; mt < 2; ++mt) {
        const int rb = grow0 + wv * 32 + mt * 16 + cn;
        if (q < 2)
            *(f32x4*)(SC + (size_t)rb * NHEADS + q * 4) = acc[mt];
    }
}

// ---------------------------------------------------------------------------
// Kernel 3 (4096 blocks x 512): fused gather + softmax + (w.z) + Wv + Wo.
//   Block = 8 cells, 8 waves, wave wv owns cell cb+wv.
//   Phase 1a: scores. lane (hh=l&7, tb=l>>3) gathers s[t][hh] for tokens
//     tb, tb+8, tb+16 (t<m: point SC row; t==m: grid SC row; else -1e30).
//     Per-head softmax via stride-8 shfl_xor reduce -> normalized w in regs.
//   Phase 1b: y_h = sum_t w_th * z_t (z in f32!). Lane owns dims {2l,2l+1}
//     x 8 heads = 16 f32 acc. Token rows 512 B coalesced; w via __shfl.
//     Pack y -> Y_s[h][cell][dims] bf16 (A-frag-ready).
//   Phase 2a: head GEMMs out_h = Y_h @ Wv_h: wave wv=h, 4 MFMAs, B-frags
//     straight from WT1 global (L2). D -> X_s[cell][h*16+d] bf16.
//   Phase 2b: zg = X_s @ Wo (as before, swapped, f32x4 store, cn<8).
//   Cell slots 8..15 of Y_s/X_s are garbage; their D rows/cols are discarded.
// LDS: Y_s 34816 + X_s 4352 = 39168 B -> 4 blocks/CU.
// ---------------------------------------------------------------------------
__global__ void __launch_bounds__(512)
k_attn_proj(const int* __restrict__ counts,
            const int* __restrict__ slots,
            const float* __restrict__ SC,
            const float* __restrict__ Xz,
            const float* __restrict__ Zg,
            const unsigned short* __restrict__ WT1g,
            const unsigned short* __restrict__ WT2g,
            float* __restrict__ zg) {
    __shared__ __align__(16) unsigned short Y_s[8][16][136];
    __shared__ __align__(16) unsigned short X_s[16][136];

    const int t    = threadIdx.x;
    const int lane = t & 63;
    const int wv   = t >> 6;                 // 0..7
    const int cb   = blockIdx.x * 8;
    const int cell = cb + wv;
    const int b    = cell >> 12;
    const int base = b * NPTS;
    const int cn   = lane & 15;
    const int q    = lane >> 4;

    // ---- phase 1a: scores + per-head softmax
    const int m = min(counts[cell], MAXP);             // wave-uniform
    int sl = (lane < MAXP) ? slots[(size_t)cell * MAXP + lane] : 0;

    const int hh = lane & 7;                 // head this lane scores
    const int tb = lane >> 3;                // token sub-index 0..7

    float sarr[3];
    #pragma unroll
    for (int p = 0; p < 3; ++p) {
        int tt = tb + 8 * p;                 // 0..23
        int pt = __shfl(sl, tt, 64);
        bool isPt = tt < m;
        bool isG  = tt == m;
        size_t r = isG ? (size_t)(NPT_ROWS + cell)
                       : (size_t)(base + (isPt ? pt : 0));
        float sc = SC[r * NHEADS + hh];
        sarr[p] = (isPt || isG) ? sc : -1e30f;
    }
    float mx = fmaxf(fmaxf(sarr[0], sarr[1]), sarr[2]);
    mx = fmaxf(mx, __shfl_xor(mx, 8, 64));
    mx = fmaxf(mx, __shfl_xor(mx, 16, 64));
    mx = fmaxf(mx, __shfl_xor(mx, 32, 64));
    float e0 = __expf(sarr[0] - mx);
    float e1 = __expf(sarr[1] - mx);
    float e2 = __expf(sarr[2] - mx);
    float sum = e0 + e1 + e2;
    sum += __shfl_xor(sum, 8, 64);
    sum += __shfl_xor(sum, 16, 64);
    sum += __shfl_xor(sum, 32, 64);
    float inv = 1.0f / sum;
    float wn0 = e0 * inv, wn1 = e1 * inv, wn2 = e2 * inv;

    // ---- phase 1b: y_h = sum_t w_th * z_t  (lane dims 2l, 2l+1; 8 heads)
    float y0[8], y1[8];
    #pragma unroll
    for (int h2 = 0; h2 < 8; ++h2) { y0[h2] = 0.0f; y1[h2] = 0.0f; }

    const int ntok = m + 1;                  // points + grid token
    for (int t0 = 0; t0 < ntok; t0 += 4) {   // chunks aligned: p const/chunk
        float wnp = (t0 < 8) ? wn0 : ((t0 < 16) ? wn1 : wn2);
        float2 zv[4];
        #pragma unroll
        for (int j = 0; j < 4; ++j) {
            int tt = t0 + j;
            int pt = __shfl(sl, tt, 64);
            const float* zr = (tt == m)
                ? (Zg + (size_t)cell * E)
                : (Xz + (size_t)(base + ((tt < m) ? pt : 0)) * E);
            zv[j] = *(const float2*)(zr + 2 * lane);
        }
        #pragma unroll
        for (int j = 0; j < 4; ++j) {
            int srcb = ((t0 + j) & 7) << 3;
            #pragma unroll
            for (int h2 = 0; h2 < 8; ++h2) {
                float w = __shfl(wnp, srcb + h2, 64);   // w[tt][h2] (0 if masked)
                y0[h2] = fmaf(w, zv[j].x, y0[h2]);
                y1[h2] = fmaf(w, zv[j].y, y1[h2]);
            }
        }
    }

    #pragma unroll
    for (int h2 = 0; h2 < 8; ++h2)
        *(unsigned*)&Y_s[h2][wv][2 * lane] = pack_bf2(y0[h2], y1[h2]);
    __syncthreads();

    // ---- phase 2a: out_h = Y_h @ Wv_h (wave wv = head wv), D -> X_s
    {
        f32x4 acc2 = f32x4{0.0f, 0.0f, 0.0f, 0.0f};
        #pragma unroll
        for (int kq = 0; kq < 4; ++kq) {
            bf16x8 aY = *(const bf16x8*)&Y_s[wv][cn][kq * 32 + q * 8];
            bf16x8 bW = *(const bf16x8*)&WT1g[(size_t)(wv * 16 + cn) * 136 + kq * 32 + q * 8];
            acc2 = __builtin_amdgcn_mfma_f32_16x16x32_bf16(aY, bW, acc2, 0, 0, 0);
        }
        #pragma unroll
        for (int r = 0; r < 4; ++r)
            X_s[q * 4 + r][wv * 16 + cn] = f2bf_rta(acc2[r]);
    }
    __syncthreads();

    // ---- phase 2b: zg[cb..cb+7][:] = X_s @ Wo (wave wv -> col tile nt=wv)
    {
        f32x4 acc3 = f32x4{0.0f, 0.0f, 0.0f, 0.0f};
        #pragma unroll
        for (int kq = 0; kq < 4; ++kq) {
            bf16x8 a   = *(const bf16x8*)&X_s[cn][kq * 32 + q * 8];
            bf16x8 bfr = *(const bf16x8*)&WT2g[(size_t)(wv * 16 + cn) * 136 + kq * 32 + q * 8];
            acc3 = __builtin_amdgcn_mfma_f32_16x16x32_bf16(bfr, a, acc3, 0, 0, 0);
        }
        if (cn < 8)   // cells 8..15 are garbage slots
            *(f32x4*)(zg + (size_t)(cb + cn) * E + wv * 16 + q * 4) = acc3;
    }
}

// ---------------------------------------------------------------------------
extern "C" void kernel_launch(void* const* d_in, const int* in_sizes, int n_in,
                              void* d_out, int out_size, void* d_ws, size_t ws_size,
                              hipStream_t stream) {
    const float* x      = (const float*)d_in[0];
    const float* z      = (const float*)d_in[1];
    const float* x_grid = (const float*)d_in[2];
    const float* z_grid = (const float*)d_in[3];
    const float* latent = (const float*)d_in[4];
    const float* Wq     = (const float*)d_in[5];
    const float* Wk     = (const float*)d_in[6];
    const float* Wv     = (const float*)d_in[7];
    const float* Wo     = (const float*)d_in[8];

    char* ws = (char*)d_ws;
    int*            counts = (int*)(ws + WS_COUNTS);
    int*            slots  = (int*)(ws + WS_SLOTS);
    unsigned short* WT1    = (unsigned short*)(ws + WS_WT1);
    unsigned short* WT2    = (unsigned short*)(ws + WS_WT2);
    float*          SC     = (float*)(ws + WS_SC);

    float* out_xgrid = (float*)d_out;                  // 65536 floats
    float* zg        = (float*)d_out + NB * NPTS;      // 32768*128 floats

    k_prep<<<9, 256, 0, stream>>>(latent, Wq, Wk, Wv, Wo, counts, WT1, WT2);

    k_main<<<1024, 256, 0, stream>>>(x, x_grid, z, z_grid, WT1,
                                     counts, slots, SC, out_xgrid);

    k_attn_proj<<<4096, 512, 0, stream>>>(counts, slots, SC, z, z_grid,
                                          WT1, WT2, zg);
}

// Round 5
// 147.616 us; speedup vs baseline: 1.0576x; 1.0576x over previous
//
#include <hip/hip_runtime.h>
#include <cstdint>
#include <cstddef>

#define S_CELLS 4096   // 64*64
#define NB      8
#define NPTS    8192
#define E       128
#define MAXP    20
#define NHEADS  8
#define NPT_ROWS 65536
#define NGR_ROWS 32768

// ws layout (bytes):
#define WS_COUNTS 0          // int[32768]        (131072)
#define WS_SLOTS  131072     // int[32768*20]     (2621440)
#define WS_WT1    2752512    // bf16 144x136      (40960 w/ pad)
#define WS_WT2    2793472    // bf16 128x136      (34816)
#define WS_SC     2828288    // float[98304*8]    (3145728)

typedef __attribute__((ext_vector_type(8))) short bf16x8;
typedef __attribute__((ext_vector_type(4))) float f32x4;
typedef __attribute__((ext_vector_type(2))) float f32x2;

__device__ __forceinline__ unsigned short f2bf_bits(float f) {   // RNE (cold paths)
    unsigned u = __float_as_uint(f);
    unsigned rounded = u + 0x7FFFu + ((u >> 16) & 1u);
    return (unsigned short)(rounded >> 16);
}
__device__ __forceinline__ unsigned short f2bf_rta(float f) {    // round-ties-away (hot)
    return (unsigned short)((__float_as_uint(f) + 0x8000u) >> 16);
}
__device__ __forceinline__ unsigned pack_bf2(float a, float b) { // [b|a] packed bf16 (RTA)
    unsigned ua = __float_as_uint(a) + 0x8000u;
    unsigned ub = __float_as_uint(b) + 0x8000u;
    return (ua >> 16) | (ub & 0xFFFF0000u);
}

// ---------------------------------------------------------------------------
// Kernel 1 (9 blocks x 256): zero counts (striped) +
//   block 0    : q = latent@Wq; A[i][h]=(Wk[i,h*16:+16].q_h)/4 -> WT1 rows
//                128..135; zero rows 136..143
//   blocks 1..4: Wv -> WT1 rows 0..127 (bf16, transposed [n][k], stride 136)
//   blocks 5..8: Wo -> WT2 (same layout)
// ---------------------------------------------------------------------------
__global__ void __launch_bounds__(256)
k_prep(const float* __restrict__ latent,
       const float* __restrict__ Wq,
       const float* __restrict__ Wk,
       const float* __restrict__ Wv,
       const float* __restrict__ Wo,
       int* __restrict__ counts,
       unsigned short* __restrict__ WT1,
       unsigned short* __restrict__ WT2) {
    const int t   = threadIdx.x;
    const int blk = blockIdx.x;

    {   // zero counts: 8192 int4s across 9*256 threads
        int4* c4 = (int4*)counts;
        for (int idx = blk * 256 + t; idx < 8192; idx += 9 * 256)
            c4[idx] = int4{0, 0, 0, 0};
    }

    if (blk == 0) {
        __shared__ float lat[E];
        __shared__ float qv[E];
        const int j = t & 127;
        if (t < E) lat[t] = latent[t];
        __syncthreads();
        float acc = 0.0f;                    // both halves compute identical q[j]
        for (int k2 = 0; k2 < E; ++k2) acc += lat[k2] * Wq[k2 * E + j];
        qv[j] = acc;
        __syncthreads();
        const int hb = (t >> 7) * 4;
        for (int h = hb; h < hb + 4; ++h) {
            float a = 0.0f;
            #pragma unroll
            for (int d = 0; d < 16; ++d) a += Wk[j * E + h * 16 + d] * qv[h * 16 + d];
            WT1[(size_t)(128 + h) * 136 + j] = f2bf_bits(a * 0.25f);
        }
        for (int idx = t; idx < 8 * 136; idx += 256) {   // zero rows 136..143
            int rr = idx / 136, cc = idx - rr * 136;
            WT1[(size_t)(136 + rr) * 136 + cc] = 0;
        }
        return;
    }

    // weight conversion: transpose via LDS, coalesced in and out
    const float* W = (blk < 5) ? Wv : Wo;
    unsigned short* WT = (blk < 5) ? WT1 : WT2;
    const int n0 = ((blk - 1) & 3) * 32;
    __shared__ float lbuf[128][33];
    #pragma unroll
    for (int it = 0; it < 16; ++it) {
        int k  = (t >> 5) + it * 8;
        int nl = t & 31;
        lbuf[k][nl] = W[(size_t)k * E + n0 + nl];
    }
    __syncthreads();
    for (int idx = t; idx < 32 * 136; idx += 256) {
        int nl = idx / 136, k = idx - nl * 136;
        float v = (k < 128) ? lbuf[k][nl] : 0.0f;
        WT[(size_t)(n0 + nl) * 136 + k] = f2bf_bits(v);
    }
}

// ---------------------------------------------------------------------------
// Kernel 2 (1024 blocks x 256): SLIM (no V materialization).
//   blocks 0..767  : SC = X @ A only (A = WT1 rows 128..143 staged, 4.4 KB).
//                    8 MFMAs/wave. Swapped operands -> lane owns row rb=..+cn,
//                    head-cols q*4+r -> one f32x4 store (q<2).
//   blocks 768..1023: per-point binning + x_grid passthrough copy.
// ---------------------------------------------------------------------------
__device__ __forceinline__ bf16x8 load_afrag_f32(const float* __restrict__ X,
                                                 int row, int kq, int q) {
    const float4* xr = (const float4*)(X + (size_t)row * E);
    float4 lo = xr[kq * 8 + q * 2];
    float4 hi = xr[kq * 8 + q * 2 + 1];
    unsigned u[4];
    u[0] = pack_bf2(lo.x, lo.y);
    u[1] = pack_bf2(lo.z, lo.w);
    u[2] = pack_bf2(hi.x, hi.y);
    u[3] = pack_bf2(hi.z, hi.w);
    union { unsigned u4[4]; bf16x8 v; } cv;
    cv.u4[0] = u[0]; cv.u4[1] = u[1]; cv.u4[2] = u[2]; cv.u4[3] = u[3];
    return cv.v;
}

__global__ void __launch_bounds__(256)
k_main(const float* __restrict__ x,
       const float* __restrict__ x_grid,
       const float* __restrict__ Xz,
       const float* __restrict__ Xg,
       const unsigned short* __restrict__ WT1g,
       int* __restrict__ counts,
       int* __restrict__ slots,
       float* __restrict__ SC,
       float* __restrict__ out_xgrid) {
    __shared__ __align__(16) unsigned short sA[16 * 136];   // 4352 B

    const int t = threadIdx.x;

    if (blockIdx.x >= 768) {                 // ---- binning + x_grid copy
        int i = (blockIdx.x - 768) * 256 + t;   // 0..65535
        out_xgrid[i] = x_grid[i];
        int b = i >> 13;
        float x0 = x[(size_t)i * 2 + 0];
        float x1 = x[(size_t)i * 2 + 1];
        int i0 = (int)rintf(x0 * 63.0f);     // RNE matches jnp.round
        int i1 = (int)rintf(x1 * 63.0f);
        i0 = min(max(i0, 0), 63);
        i1 = min(max(i1, 0), 63);
        int cell = b * S_CELLS + i0 * 64 + i1;
        int slot = atomicAdd(&counts[cell], 1);
        if (slot < MAXP) slots[(size_t)cell * MAXP + slot] = i & (NPTS - 1);
        return;
    }

    {   // stage A image: WT1 rows 128..143 (16x136 bf16 = 272 float4)
        const float4* src = (const float4*)(WT1g + 128 * 136);
        float4* dst = (float4*)sA;
        if (t < 272) dst[t] = src[t];
    }
    __syncthreads();

    const int lane = t & 63;
    const int wv   = t >> 6;
    const int cn   = lane & 15;
    const int q    = lane >> 4;

    const int grow0 = blockIdx.x * 128;
    const float* Xsrc;
    int srow;
    if (blockIdx.x < 512) { Xsrc = Xz; srow = grow0; }
    else                  { Xsrc = Xg; srow = grow0 - NPT_ROWS; }

    f32x4 acc[2];
    acc[0] = f32x4{0.0f, 0.0f, 0.0f, 0.0f};
    acc[1] = f32x4{0.0f, 0.0f, 0.0f, 0.0f};

    #pragma unroll
    for (int kq = 0; kq < 4; ++kq) {
        const bf16x8 b = *(const bf16x8*)&sA[cn * 136 + kq * 32 + q * 8];
        #pragma unroll
        for (int mt = 0; mt < 2; ++mt) {
            bf16x8 a = load_afrag_f32(Xsrc, srow + wv * 32 + mt * 16 + cn, kq, q);
            acc[mt] = __builtin_amdgcn_mfma_f32_16x16x32_bf16(b, a, acc[mt], 0, 0, 0);
        }
    }

    // swapped-D: lane owns row rb, head-cols q*4+{0..3}; cols 8..15 hit the
    // zero rows of A (WT1 rows 136..143) -> only q<2 stores.
    #pragma unroll
    for (int mt = 0; mt < 2; ++mt) {
        const int rb = grow0 + wv * 32 + mt * 16 + cn;
        if (q < 2)
            *(f32x4*)(SC + (size_t)rb * NHEADS + q * 4) = acc[mt];
    }
}

// ---------------------------------------------------------------------------
// Kernel 3 (4096 blocks x 512): fused gather + softmax + (w.z) + Wv + Wo.
//   Block = 8 cells, 8 waves, wave wv owns cell cb+wv.
//   Phase 1a: scores (lane (hh=l&7, tb=l>>3) covers tokens tb,tb+8,tb+16)
//     + per-head softmax via stride-8 shfl_xor. Weights -> w_lds[cell][t][h]
//     (masked tokens write exact 0.0).
//   Phase 1b: y_h = sum_t w_th * z_t. Lane owns dims {2l,2l+1}; w read from
//     w_lds as two float4 with WAVE-UNIFORM address (broadcast, conflict-
//     free) -> 2 LDS ops/token instead of 8 shfl. Accumulate in f32x2 so
//     clang can emit v_pk_fma_f32. Pack y -> Y_s[h][cell][dims] bf16.
//   Phase 2a: out_h = Y_h @ Wv_h (wave wv = head), B-frags from WT1 (L2).
//   Phase 2b: zg = X_s @ Wo (swapped, one f32x4 store, cn<8).
// LDS: Y_s 34816 + X_s 4352 + w_lds 6144 = 45312 B -> 3 blocks/CU.
// ---------------------------------------------------------------------------
__global__ void __launch_bounds__(512)
k_attn_proj(const int* __restrict__ counts,
            const int* __restrict__ slots,
            const float* __restrict__ SC,
            const float* __restrict__ Xz,
            const float* __restrict__ Zg,
            const unsigned short* __restrict__ WT1g,
            const unsigned short* __restrict__ WT2g,
            float* __restrict__ zg) {
    __shared__ __align__(16) unsigned short Y_s[8][16][136];
    __shared__ __align__(16) unsigned short X_s[16][136];
    __shared__ __align__(16) float w_lds[8][24][8];   // [cell][token][head]

    const int t    = threadIdx.x;
    const int lane = t & 63;
    const int wv   = t >> 6;                 // 0..7
    const int cb   = blockIdx.x * 8;
    const int cell = cb + wv;
    const int b    = cell >> 12;
    const int base = b * NPTS;
    const int cn   = lane & 15;
    const int q    = lane >> 4;

    // ---- phase 1a: scores + per-head softmax
    const int m = min(counts[cell], MAXP);             // wave-uniform
    int sl = (lane < MAXP) ? slots[(size_t)cell * MAXP + lane] : 0;

    const int hh = lane & 7;                 // head this lane scores
    const int tb = lane >> 3;                // token sub-index 0..7

    float sarr[3];
    #pragma unroll
    for (int p = 0; p < 3; ++p) {
        int tt = tb + 8 * p;                 // 0..23
        int pt = __shfl(sl, tt, 64);
        bool isPt = tt < m;
        bool isG  = tt == m;
        size_t r = isG ? (size_t)(NPT_ROWS + cell)
                       : (size_t)(base + (isPt ? pt : 0));
        float sc = SC[r * NHEADS + hh];
        sarr[p] = (isPt || isG) ? sc : -1e30f;
    }
    float mx = fmaxf(fmaxf(sarr[0], sarr[1]), sarr[2]);
    mx = fmaxf(mx, __shfl_xor(mx, 8, 64));
    mx = fmaxf(mx, __shfl_xor(mx, 16, 64));
    mx = fmaxf(mx, __shfl_xor(mx, 32, 64));
    float e0 = __expf(sarr[0] - mx);
    float e1 = __expf(sarr[1] - mx);
    float e2 = __expf(sarr[2] - mx);
    float sum = e0 + e1 + e2;
    sum += __shfl_xor(sum, 8, 64);
    sum += __shfl_xor(sum, 16, 64);
    sum += __shfl_xor(sum, 32, 64);
    float inv = 1.0f / sum;

    // weights -> LDS (masked tokens get exact 0.0; covers t = 0..23)
    w_lds[wv][tb][hh]      = e0 * inv;
    w_lds[wv][tb + 8][hh]  = e1 * inv;
    w_lds[wv][tb + 16][hh] = e2 * inv;

    // ---- phase 1b: y_h = sum_t w_th * z_t  (lane dims 2l, 2l+1)
    f32x2 y[8];
    #pragma unroll
    for (int h2 = 0; h2 < 8; ++h2) y[h2] = f32x2{0.0f, 0.0f};

    const int ntok = m + 1;                  // points + grid token
    for (int t0 = 0; t0 < ntok; t0 += 4) {
        f32x2 zv[4];
        #pragma unroll
        for (int j = 0; j < 4; ++j) {
            int tt = t0 + j;
            int pt = __shfl(sl, tt, 64);
            const float* zr = (tt == m)
                ? (Zg + (size_t)cell * E)
                : (Xz + (size_t)(base + ((tt < m) ? pt : 0)) * E);
            zv[j] = *(const f32x2*)(zr + 2 * lane);
        }
        #pragma unroll
        for (int j = 0; j < 4; ++j) {
            int tt = t0 + j;                 // <= 23: w_lds covers, masked -> 0
            const float4 wA = *(const float4*)&w_lds[wv][tt][0];
            const float4 wB = *(const float4*)&w_lds[wv][tt][4];
            y[0] += zv[j] * wA.x;
            y[1] += zv[j] * wA.y;
            y[2] += zv[j] * wA.z;
            y[3] += zv[j] * wA.w;
            y[4] += zv[j] * wB.x;
            y[5] += zv[j] * wB.y;
            y[6] += zv[j] * wB.z;
            y[7] += zv[j] * wB.w;
        }
    }

    #pragma unroll
    for (int h2 = 0; h2 < 8; ++h2)
        *(unsigned*)&Y_s[h2][wv][2 * lane] = pack_bf2(y[h2].x, y[h2].y);
    __syncthreads();

    // ---- phase 2a: out_h = Y_h @ Wv_h (wave wv = head wv), D -> X_s
    {
        f32x4 acc2 = f32x4{0.0f, 0.0f, 0.0f, 0.0f};
        #pragma unroll
        for (int kq = 0; kq < 4; ++kq) {
            bf16x8 aY = *(const bf16x8*)&Y_s[wv][cn][kq * 32 + q * 8];
            bf16x8 bW = *(const bf16x8*)&WT1g[(size_t)(wv * 16 + cn) * 136 + kq * 32 + q * 8];
            acc2 = __builtin_amdgcn_mfma_f32_16x16x32_bf16(aY, bW, acc2, 0, 0, 0);
        }
        #pragma unroll
        for (int r = 0; r < 4; ++r)
            X_s[q * 4 + r][wv * 16 + cn] = f2bf_rta(acc2[r]);
    }
    __syncthreads();

    // ---- phase 2b: zg[cb..cb+7][:] = X_s @ Wo (wave wv -> col tile nt=wv)
    {
        f32x4 acc3 = f32x4{0.0f, 0.0f, 0.0f, 0.0f};
        #pragma unroll
        for (int kq = 0; kq < 4; ++kq) {
            bf16x8 a   = *(const bf16x8*)&X_s[cn][kq * 32 + q * 8];
            bf16x8 bfr = *(const bf16x8*)&WT2g[(size_t)(wv * 16 + cn) * 136 + kq * 32 + q * 8];
            acc3 = __builtin_amdgcn_mfma_f32_16x16x32_bf16(bfr, a, acc3, 0, 0, 0);
        }
        if (cn < 8)   // cells 8..15 are garbage slots
            *(f32x4*)(zg + (size_t)(cb + cn) * E + wv * 16 + q * 4) = acc3;
    }
}

// ---------------------------------------------------------------------------
extern "C" void kernel_launch(void* const* d_in, const int* in_sizes, int n_in,
                              void* d_out, int out_size, void* d_ws, size_t ws_size,
                              hipStream_t stream) {
    const float* x      = (const float*)d_in[0];
    const float* z      = (const float*)d_in[1];
    const float* x_grid = (const float*)d_in[2];
    const float* z_grid = (const float*)d_in[3];
    const float* latent = (const float*)d_in[4];
    const float* Wq     = (const float*)d_in[5];
    const float* Wk     = (const float*)d_in[6];
    const float* Wv     = (const float*)d_in[7];
    const float* Wo     = (const float*)d_in[8];

    char* ws = (char*)d_ws;
    int*            counts = (int*)(ws + WS_COUNTS);
    int*            slots  = (int*)(ws + WS_SLOTS);
    unsigned short* WT1    = (unsigned short*)(ws + WS_WT1);
    unsigned short* WT2    = (unsigned short*)(ws + WS_WT2);
    float*          SC     = (float*)(ws + WS_SC);

    float* out_xgrid = (float*)d_out;                  // 65536 floats
    float* zg        = (float*)d_out + NB * NPTS;      // 32768*128 floats

    k_prep<<<9, 256, 0, stream>>>(latent, Wq, Wk, Wv, Wo, counts, WT1, WT2);

    k_main<<<1024, 256, 0, stream>>>(x, x_grid, z, z_grid, WT1,
                                     counts, slots, SC, out_xgrid);

    k_attn_proj<<<4096, 512, 0, stream>>>(counts, slots, SC, z, z_grid,
                                          WT1, WT2, zg);
}

// Round 6
// 140.540 us; speedup vs baseline: 1.1108x; 1.0503x over previous
//
#include <hip/hip_runtime.h>
#include <cstdint>
#include <cstddef>

#define S_CELLS 4096   // 64*64
#define NB      8
#define NPTS    8192
#define E       128
#define MAXP    20
#define NHEADS  8
#define NPT_ROWS 65536
#define NGR_ROWS 32768

// ws layout (bytes):
#define WS_COUNTS 0          // int[32768]        (131072)
#define WS_SLOTS  131072     // int[32768*20]     (2621440)
#define WS_WT1    2752512    // bf16 144x136      (40960 w/ pad)
#define WS_WT2    2793472    // bf16 128x136      (34816)
#define WS_SC     2828288    // float[98304*8]    (3145728)
#define WS_V      5974016    // bf16[98304*128]   (25165824)

typedef __attribute__((ext_vector_type(8))) short bf16x8;
typedef __attribute__((ext_vector_type(4))) float f32x4;

__device__ __forceinline__ unsigned short f2bf_bits(float f) {   // RNE (cold paths)
    unsigned u = __float_as_uint(f);
    unsigned rounded = u + 0x7FFFu + ((u >> 16) & 1u);
    return (unsigned short)(rounded >> 16);
}
__device__ __forceinline__ unsigned short f2bf_rta(float f) {    // round-ties-away (hot)
    return (unsigned short)((__float_as_uint(f) + 0x8000u) >> 16);
}
__device__ __forceinline__ unsigned pack_bf2(float a, float b) { // [b|a] packed bf16
    unsigned ua = __float_as_uint(a) + 0x8000u;
    unsigned ub = __float_as_uint(b) + 0x8000u;
    return (ua >> 16) | (ub & 0xFFFF0000u);
}
__device__ __forceinline__ float bf2f(unsigned short u) {
    return __uint_as_float(((unsigned)u) << 16);
}

// ---------------------------------------------------------------------------
// Kernel 1 (9 blocks x 256): zero counts (striped) +
//   block 0    : q = latent@Wq; A[i][h]=(Wk[i,h*16:+16].q_h)/4 -> WT1 rows
//                128..135; zero rows 136..143
//   blocks 1..4: Wv -> WT1 rows 0..127 (bf16, transposed [n][k], stride 136)
//   blocks 5..8: Wo -> WT2 (same layout)
// ---------------------------------------------------------------------------
__global__ void __launch_bounds__(256)
k_prep(const float* __restrict__ latent,
       const float* __restrict__ Wq,
       const float* __restrict__ Wk,
       const float* __restrict__ Wv,
       const float* __restrict__ Wo,
       int* __restrict__ counts,
       unsigned short* __restrict__ WT1,
       unsigned short* __restrict__ WT2) {
    const int t   = threadIdx.x;
    const int blk = blockIdx.x;

    {   // zero counts: 8192 int4s across 9*256 threads
        int4* c4 = (int4*)counts;
        for (int idx = blk * 256 + t; idx < 8192; idx += 9 * 256)
            c4[idx] = int4{0, 0, 0, 0};
    }

    if (blk == 0) {
        __shared__ float lat[E];
        __shared__ float qv[E];
        const int j = t & 127;
        if (t < E) lat[t] = latent[t];
        __syncthreads();
        float acc = 0.0f;                    // both halves compute identical q[j]
        for (int k2 = 0; k2 < E; ++k2) acc += lat[k2] * Wq[k2 * E + j];
        qv[j] = acc;
        __syncthreads();
        const int hb = (t >> 7) * 4;
        for (int h = hb; h < hb + 4; ++h) {
            float a = 0.0f;
            #pragma unroll
            for (int d = 0; d < 16; ++d) a += Wk[j * E + h * 16 + d] * qv[h * 16 + d];
            WT1[(size_t)(128 + h) * 136 + j] = f2bf_bits(a * 0.25f);
        }
        for (int idx = t; idx < 8 * 136; idx += 256) {   // zero rows 136..143
            int rr = idx / 136, cc = idx - rr * 136;
            WT1[(size_t)(136 + rr) * 136 + cc] = 0;
        }
        return;
    }

    // weight conversion: transpose via LDS, coalesced in and out
    const float* W = (blk < 5) ? Wv : Wo;
    unsigned short* WT = (blk < 5) ? WT1 : WT2;
    const int n0 = ((blk - 1) & 3) * 32;
    __shared__ float lbuf[128][33];
    #pragma unroll
    for (int it = 0; it < 16; ++it) {
        int k  = (t >> 5) + it * 8;
        int nl = t & 31;
        lbuf[k][nl] = W[(size_t)k * E + n0 + nl];
    }
    __syncthreads();
    for (int idx = t; idx < 32 * 136; idx += 256) {
        int nl = idx / 136, k = idx - nl * 136;
        float v = (k < 128) ? lbuf[k][nl] : 0.0f;
        WT[(size_t)(n0 + nl) * 136 + k] = f2bf_bits(v);
    }
}

// ---------------------------------------------------------------------------
// Kernel 2 (1024 blocks x 256):
//   blocks 0..767  : MFMA GEMM  V = [z; z_grid] @ Wv (bf16) + SC = X @ A
//   blocks 768..1023: per-point binning + x_grid passthrough copy
//     (independent of GEMM; hidden behind it. counts pre-zeroed by k_prep.)
// GEMM: WT1 image staged by linear float4 copy; 4 waves x MT=2 = 128 rows/blk.
// W_t trimmed to exactly 144x136x2 = 39168 B -> 4 blocks/CU (was 40960 -> 3).
// Layouts (HW-verified): A-frag m=lane&15, k=kq*32+q*8+j; B-frag n=lane&15
// same k; C/D col=lane&15, row=q*4+r.
// ---------------------------------------------------------------------------
__device__ __forceinline__ bf16x8 load_afrag_f32(const float* __restrict__ X,
                                                 int row, int kq, int q) {
    const float4* xr = (const float4*)(X + (size_t)row * E);
    float4 lo = xr[kq * 8 + q * 2];
    float4 hi = xr[kq * 8 + q * 2 + 1];
    unsigned u[4];
    u[0] = pack_bf2(lo.x, lo.y);
    u[1] = pack_bf2(lo.z, lo.w);
    u[2] = pack_bf2(hi.x, hi.y);
    u[3] = pack_bf2(hi.z, hi.w);
    union { unsigned u4[4]; bf16x8 v; } cv;
    cv.u4[0] = u[0]; cv.u4[1] = u[1]; cv.u4[2] = u[2]; cv.u4[3] = u[3];
    return cv.v;
}

__global__ void __launch_bounds__(256)
k_main(const float* __restrict__ x,
       const float* __restrict__ x_grid,
       const float* __restrict__ Xz,
       const float* __restrict__ Xg,
       const unsigned short* __restrict__ WT1g,
       int* __restrict__ counts,
       int* __restrict__ slots,
       unsigned short* __restrict__ V,
       float* __restrict__ SC,
       float* __restrict__ out_xgrid) {
    __shared__ unsigned short W_t[19584];    // 39168 B exactly -> 4 blocks/CU

    const int t = threadIdx.x;

    if (blockIdx.x >= 768) {                 // ---- binning + x_grid copy
        int i = (blockIdx.x - 768) * 256 + t;   // 0..65535
        out_xgrid[i] = x_grid[i];
        int b = i >> 13;
        float x0 = x[(size_t)i * 2 + 0];
        float x1 = x[(size_t)i * 2 + 1];
        int i0 = (int)rintf(x0 * 63.0f);     // RNE matches jnp.round
        int i1 = (int)rintf(x1 * 63.0f);
        i0 = min(max(i0, 0), 63);
        i1 = min(max(i1, 0), 63);
        int cell = b * S_CELLS + i0 * 64 + i1;
        int slot = atomicAdd(&counts[cell], 1);
        if (slot < MAXP) slots[(size_t)cell * MAXP + slot] = i & (NPTS - 1);
        return;
    }

    {   // linear stage of WT1 image: 2448 float4 (no transpose -> no conflicts)
        const float4* src = (const float4*)WT1g;
        float4* dst = (float4*)W_t;
        #pragma unroll
        for (int it = 0; it < 10; ++it) {
            int idx = t + it * 256;
            if (idx < 2448) dst[idx] = src[idx];
        }
    }
    __syncthreads();

    const int lane = t & 63;
    const int wv   = t >> 6;
    const int cn   = lane & 15;
    const int q    = lane >> 4;

    const int grow0 = blockIdx.x * 128;
    const float* Xsrc;
    int srow;
    if (blockIdx.x < 512) { Xsrc = Xz; srow = grow0; }
    else                  { Xsrc = Xg; srow = grow0 - NPT_ROWS; }

    f32x4 acc[2][9];
    #pragma unroll
    for (int mt = 0; mt < 2; ++mt)
        #pragma unroll
        for (int nt = 0; nt < 9; ++nt)
            acc[mt][nt] = f32x4{0.0f, 0.0f, 0.0f, 0.0f};

    #pragma unroll
    for (int kq = 0; kq < 4; ++kq) {
        bf16x8 a[2];
        #pragma unroll
        for (int mt = 0; mt < 2; ++mt)
            a[mt] = load_afrag_f32(Xsrc, srow + wv * 32 + mt * 16 + cn, kq, q);
        #pragma unroll
        for (int nt = 0; nt < 9; ++nt) {
            const bf16x8 b = *(const bf16x8*)&W_t[(size_t)(nt * 16 + cn) * 136 + kq * 32 + q * 8];
            #pragma unroll
            for (int mt = 0; mt < 2; ++mt)
                acc[mt][nt] = __builtin_amdgcn_mfma_f32_16x16x32_bf16(
                    a[mt], b, acc[mt][nt], 0, 0, 0);
        }
    }

    #pragma unroll
    for (int mt = 0; mt < 2; ++mt) {
        const int rb = grow0 + wv * 32 + mt * 16 + q * 4;
        #pragma unroll
        for (int nt = 0; nt < 8; ++nt)
            #pragma unroll
            for (int r = 0; r < 4; ++r)
                V[(size_t)(rb + r) * E + nt * 16 + cn] = f2bf_rta(acc[mt][nt][r]);
        if (cn < 8) {
            #pragma unroll
            for (int r = 0; r < 4; ++r)
                SC[(size_t)(rb + r) * NHEADS + cn] = acc[mt][8][r];
        }
    }
}

// ---------------------------------------------------------------------------
// Kernel 3 (2048 blocks x 1024): fused attention + Wo projection.
//   Block = 16 cells, 16 waves; wave wv gathers cell cb+wv. NEW: the block's
//   counts + slots (contiguous: slots[cb*20 .. cb*20+319], counts[cb..cb+15])
//   are prefetched COALESCED into LDS once -> removes two serial scattered
//   round-trips from every wave's dependency chain; sl_s LDS broadcast
//   replaces the __shfl chain. sl_s padded to [16][24], cols 20..23 zeroed,
//   so t0+j (< m+4 <= 23) never reads garbage.
//   Lane owns cols {2l,2l+1} (head h=l>>3 -> one softmax state, packed uint
//   V loads). Result -> X_s[wv] (bf16, A-frag-ready). Phase 2: waves 0..7
//   hold Wo B-frags for nt=wv in REGISTERS -> 4 MFMAs each.
// LDS: 4352 + 1536 + 64 = 5952 B.
// ---------------------------------------------------------------------------
__global__ void __launch_bounds__(1024)
k_attn_proj(const int* __restrict__ counts,
            const int* __restrict__ slots,
            const float* __restrict__ SC,
            const unsigned short* __restrict__ Vg,
            const unsigned short* __restrict__ WT2g,
            float* __restrict__ zg) {
    __shared__ __align__(16) unsigned short X_s[16][136];
    __shared__ int sl_s[16][MAXP + 4];       // cols 20..23 zeroed
    __shared__ int cnt_s[16];

    const int t    = threadIdx.x;
    const int lane = t & 63;
    const int wv   = t >> 6;                 // 0..15
    const int cb   = blockIdx.x * 16;
    const int b    = cb >> 12;
    const int base = b * NPTS;
    const int cn   = lane & 15;
    const int q    = lane >> 4;

    // ---- block-level coalesced prefetch of counts + slots
    if (t < 320) {
        int c = t / MAXP, s = t - c * MAXP;
        sl_s[c][s] = slots[(size_t)cb * MAXP + t];   // linear = [16][20] row-major
    } else if (t < 336) {
        cnt_s[t - 320] = counts[cb + (t - 320)];
    } else if (t < 400) {
        int i = t - 336;                     // zero pad cols 20..23
        sl_s[i >> 2][MAXP + (i & 3)] = 0;
    }

    // preload Wo B-fragments (nt = wv for waves 0..7) — independent of phase 1
    bf16x8 bfr[4];
    if (wv < 8) {
        #pragma unroll
        for (int kq = 0; kq < 4; ++kq)
            bfr[kq] = *(const bf16x8*)&WT2g[(size_t)(wv * 16 + cn) * 136 + kq * 32 + q * 8];
    }
    __syncthreads();

    // ---- phase 1: gather + online softmax for cell cb+wv
    const int cell = cb + wv;
    const int m    = min(cnt_s[wv], MAXP);             // wave-uniform (LDS)
    const int h    = lane >> 3;

    size_t r0 = (size_t)(NPT_ROWS + cell);
    float mm = SC[r0 * NHEADS + h];
    float ss = 1.0f;
    unsigned v0 = *(const unsigned*)(Vg + r0 * E + 2 * lane);
    float o0 = bf2f((unsigned short)v0);
    float o1 = bf2f((unsigned short)(v0 >> 16));

    for (int t0 = 0; t0 < m; t0 += 4) {
        float av[4], p0[4], p1[4];
        #pragma unroll
        for (int j = 0; j < 4; ++j) {
            int tt = t0 + j;
            int pt = sl_s[wv][tt];           // LDS broadcast (pad -> 0)
            bool val = tt < m;
            pt = val ? pt : 0;
            size_t r = (size_t)(base + pt);
            float sa = SC[r * NHEADS + h];
            av[j] = val ? sa : -1e30f;       // masked -> e=0, alpha=1: exact no-op
            unsigned vv = *(const unsigned*)(Vg + r * E + 2 * lane);
            p0[j] = bf2f((unsigned short)vv);
            p1[j] = bf2f((unsigned short)(vv >> 16));
        }
        #pragma unroll
        for (int j = 0; j < 4; ++j) {
            float nm = fmaxf(mm, av[j]);
            float e  = __expf(av[j] - nm);
            float al = __expf(mm - nm);
            ss = ss * al + e;
            o0 = o0 * al + e * p0[j];
            o1 = o1 * al + e * p1[j];
            mm = nm;
        }
    }
    float inv = 1.0f / ss;
    *(unsigned*)&X_s[wv][2 * lane] = pack_bf2(o0 * inv, o1 * inv);
    __syncthreads();

    // ---- phase 2: zg[cb..cb+15][:] = X_s @ Wo  (wave wv -> col tile nt=wv)
    if (wv < 8) {
        f32x4 acc = f32x4{0.0f, 0.0f, 0.0f, 0.0f};
        #pragma unroll
        for (int kq = 0; kq < 4; ++kq) {
            bf16x8 a = *(const bf16x8*)&X_s[cn][kq * 32 + q * 8];
            acc = __builtin_amdgcn_mfma_f32_16x16x32_bf16(a, bfr[kq], acc, 0, 0, 0);
        }
        #pragma unroll
        for (int r = 0; r < 4; ++r)
            zg[(size_t)(cb + q * 4 + r) * E + wv * 16 + cn] = acc[r];
    }
}

// ---------------------------------------------------------------------------
extern "C" void kernel_launch(void* const* d_in, const int* in_sizes, int n_in,
                              void* d_out, int out_size, void* d_ws, size_t ws_size,
                              hipStream_t stream) {
    const float* x      = (const float*)d_in[0];
    const float* z      = (const float*)d_in[1];
    const float* x_grid = (const float*)d_in[2];
    const float* z_grid = (const float*)d_in[3];
    const float* latent = (const float*)d_in[4];
    const float* Wq     = (const float*)d_in[5];
    const float* Wk     = (const float*)d_in[6];
    const float* Wv     = (const float*)d_in[7];
    const float* Wo     = (const float*)d_in[8];

    char* ws = (char*)d_ws;
    int*            counts = (int*)(ws + WS_COUNTS);
    int*            slots  = (int*)(ws + WS_SLOTS);
    unsigned short* WT1    = (unsigned short*)(ws + WS_WT1);
    unsigned short* WT2    = (unsigned short*)(ws + WS_WT2);
    float*          SC     = (float*)(ws + WS_SC);
    unsigned short* V      = (unsigned short*)(ws + WS_V);

    float* out_xgrid = (float*)d_out;                  // 65536 floats
    float* zg        = (float*)d_out + NB * NPTS;      // 32768*128 floats

    k_prep<<<9, 256, 0, stream>>>(latent, Wq, Wk, Wv, Wo, counts, WT1, WT2);

    k_main<<<1024, 256, 0, stream>>>(x, x_grid, z, z_grid, WT1,
                                     counts, slots, V, SC, out_xgrid);

    k_attn_proj<<<2048, 1024, 0, stream>>>(counts, slots, SC, V, WT2, zg);
}